// Round 9
// baseline (163.839 us; speedup 1.0000x reference)
//
#include <hip/hip_runtime.h>
#include <math.h>

#define T_LEN 256
#define HID 10

typedef float v2f __attribute__((ext_vector_type(2)));

__device__ __forceinline__ v2f mk2(float a, float b) { v2f r; r.x = a; r.y = b; return r; }
__device__ __forceinline__ v2f splat2(float a) { return mk2(a, a); }

// setup-only accurate softplus
__device__ __forceinline__ float softplus_f(float x) {
    return fmaxf(x, 0.0f) + log1pf(expf(-fabsf(x)));
}
__device__ __forceinline__ float samp(const float* mu, const float* rho,
                                      const float* eps, int i) {
    return mu[i] + softplus_f(rho[i]) * eps[i];
}

#define NLOG2E (-1.442695040888963f)   // i,f,o gate-input pre-scale
#define P2LOG2E (2.885390081777927f)   // g gate-input pre-scale (and c-state scale)

// gate activations on PRE-SCALED inputs (scale folded into weights):
__device__ __forceinline__ float sig_pre(float a) {
    return __builtin_amdgcn_rcpf(1.0f + __builtin_amdgcn_exp2f(a));
}
// g-gate tanh with OUTPUT scaled by P2LOG2E (c kept as cs = P2LOG2E*c)
__device__ __forceinline__ float g_act_scaled(float a) {
    return fmaf(-2.0f * P2LOG2E,
                __builtin_amdgcn_rcpf(__builtin_amdgcn_exp2f(a) + 1.0f),
                P2LOG2E);
}
// tanh(c) from pre-scaled state cs = 2log2e*c
__device__ __forceinline__ float tanh_from_cs(float cs) {
    return fmaf(-2.0f, __builtin_amdgcn_rcpf(__builtin_amdgcn_exp2f(cs) + 1.0f), 1.0f);
}

struct Wreg {
    v2f whh01[HID], whh23[HID];   // recurrent cols {i,f} / {g,o}, pre-scaled
    v2f wih01, wih23, b01, b23;   // pre-scaled
};

// one LSTM step; h in 3 float4s (h[0..9] + 2 zero pads). 4-deep FMA tree.
// (identical to the proven R5 step)
__device__ __forceinline__ float lstm_step(const Wreg& w, float xt,
                                           float4 h0, float4 h1, float4 h2,
                                           float& cs)
{
    v2f x2 = splat2(xt);
    v2f A1 = __builtin_elementwise_fma(x2, w.wih01, w.b01);
    v2f A3 = __builtin_elementwise_fma(x2, w.wih23, w.b23);
    A1 = __builtin_elementwise_fma(splat2(h0.x), w.whh01[0], A1);
    A3 = __builtin_elementwise_fma(splat2(h0.x), w.whh23[0], A3);
    v2f B1 = w.whh01[2] * splat2(h0.z);
    v2f B3 = w.whh23[2] * splat2(h0.z);
    v2f C1 = w.whh01[1] * splat2(h0.y);
    v2f C3 = w.whh23[1] * splat2(h0.y);
    v2f D1 = w.whh01[3] * splat2(h0.w);
    v2f D3 = w.whh23[3] * splat2(h0.w);
    A1 = __builtin_elementwise_fma(splat2(h1.x), w.whh01[4], A1);
    A3 = __builtin_elementwise_fma(splat2(h1.x), w.whh23[4], A3);
    B1 = __builtin_elementwise_fma(splat2(h1.z), w.whh01[6], B1);
    B3 = __builtin_elementwise_fma(splat2(h1.z), w.whh23[6], B3);
    C1 = __builtin_elementwise_fma(splat2(h1.y), w.whh01[5], C1);
    C3 = __builtin_elementwise_fma(splat2(h1.y), w.whh23[5], C3);
    D1 = __builtin_elementwise_fma(splat2(h1.w), w.whh01[7], D1);
    D3 = __builtin_elementwise_fma(splat2(h1.w), w.whh23[7], D3);
    A1 = __builtin_elementwise_fma(splat2(h2.x), w.whh01[8], A1);
    A3 = __builtin_elementwise_fma(splat2(h2.x), w.whh23[8], A3);
    C1 = __builtin_elementwise_fma(splat2(h2.y), w.whh01[9], C1);
    C3 = __builtin_elementwise_fma(splat2(h2.y), w.whh23[9], C3);
    v2f a01 = (A1 + B1) + (C1 + D1);
    v2f a23 = (A3 + B3) + (C3 + D3);
    float ig = sig_pre(a01.x);
    float fg = sig_pre(a01.y);
    float gg = g_act_scaled(a23.x);
    float og = sig_pre(a23.y);
    cs = fmaf(fg, cs, ig * gg);          // cs = P2LOG2E * c
    return og * tanh_from_cs(cs);
}

// One wave per block; 4 elements/wave (one per 16-lane slot), 2048 blocks =
// EXACTLY 2 waves per SIMD on every SIMD (no stragglers). Lean DS diet:
// 1 ds_write + 3 broadcast ds_read_b128 per wave-step (x is per-lane float4,
// no shuffles). While one wave sleeps on the LDS round-trip, the co-resident
// wave issues its step -> the ~390ns chain of the 1-wave rounds is paid
// concurrently. Slot stride 20 floats: the 3 broadcast reads are
// bank-quad-disjoint across the 4 slots.
__global__ __launch_bounds__(64) void bayes_lstm_kernel(
    const float* __restrict__ x,
    const float* __restrict__ w_ih_mu, const float* __restrict__ w_ih_rho,
    const float* __restrict__ w_hh_mu, const float* __restrict__ w_hh_rho,
    const float* __restrict__ b_mu,    const float* __restrict__ b_rho,
    const float* __restrict__ eps_ih,  const float* __restrict__ eps_hh,
    const float* __restrict__ eps_b,
    const float* __restrict__ lin_w,   const float* __restrict__ lin_b,
    float* __restrict__ out, int n_elem)
{
    __shared__ __align__(16) float hbuf[4 * 20];

    const int lane = threadIdx.x & 63;
    const int k    = lane & 15;          // unit index (active k < 10)
    const int slot = lane >> 4;          // 0..3
    const int b    = blockIdx.x * 4 + slot;
    const int b_eff = (b < n_elem) ? b : (n_elem - 1);   // clamp for safe loads
    const bool un  = (k < HID);
    float* hb = hbuf + slot * 20;

    // ---- sample weights into registers, PRE-SCALED (k<10 lanes only; pad
    // lanes get zero weights -> their hk stays exactly 0) ----
    Wreg w;
    w.wih01 = splat2(0.f); w.wih23 = splat2(0.f);
    w.b01 = splat2(0.f);   w.b23 = splat2(0.f);
#pragma unroll
    for (int j = 0; j < HID; ++j) { w.whh01[j] = splat2(0.f); w.whh23[j] = splat2(0.f); }
    const v2f s01 = mk2(NLOG2E, NLOG2E);      // {i, f}
    const v2f s23 = mk2(P2LOG2E, NLOG2E);     // {g, o}
    if (un) {
        const int c0 = k, c1 = HID + k, c2 = 2 * HID + k, c3 = 3 * HID + k;
        w.wih01 = s01 * mk2(samp(w_ih_mu, w_ih_rho, eps_ih, c0), samp(w_ih_mu, w_ih_rho, eps_ih, c1));
        w.wih23 = s23 * mk2(samp(w_ih_mu, w_ih_rho, eps_ih, c2), samp(w_ih_mu, w_ih_rho, eps_ih, c3));
        w.b01   = s01 * mk2(samp(b_mu, b_rho, eps_b, c0), samp(b_mu, b_rho, eps_b, c1));
        w.b23   = s23 * mk2(samp(b_mu, b_rho, eps_b, c2), samp(b_mu, b_rho, eps_b, c3));
#pragma unroll
        for (int j = 0; j < HID; ++j) {
            w.whh01[j] = s01 * mk2(samp(w_hh_mu, w_hh_rho, eps_hh, j * 4 * HID + c0),
                                   samp(w_hh_mu, w_hh_rho, eps_hh, j * 4 * HID + c1));
            w.whh23[j] = s23 * mk2(samp(w_hh_mu, w_hh_rho, eps_hh, j * 4 * HID + c2),
                                   samp(w_hh_mu, w_hh_rho, eps_hh, j * 4 * HID + c3));
        }
    }

    // zero the 2 pad words once (lanes 10,11 rewrite 0 there every step too)
    if (k < 2) hb[16 + k] = 0.f;         // words 16,17 unused but keep clean
    if (k >= 10 && k < 12) hb[k] = 0.f;  // pads read by h2.zw

    // ---- recurrence: 64 chunks x 4 steps, x prefetched one chunk ahead ----
    float cs = 0.f, hk = 0.f;
    float4 h0 = make_float4(0.f, 0.f, 0.f, 0.f);
    float4 h1 = h0, h2 = h0;
    const float4* p  = (const float4*)hb;
    const float4* xv = (const float4*)(x + (size_t)b_eff * T_LEN);
    float4 xq = xv[0];

    for (int ch = 0; ch < 64; ++ch) {    // 64 chunks x 4 steps = 256
        const int nx = (ch < 63) ? ch + 1 : 63;
        float4 xn = xv[nx];              // prefetch next chunk
#pragma unroll
        for (int ti = 0; ti < 4; ++ti) {
            float xt = (ti == 0) ? xq.x : (ti == 1) ? xq.y : (ti == 2) ? xq.z : xq.w;
            hk = lstm_step(w, xt, h0, h1, h2, cs);
            hb[k] = hk;                  // write own h (pad lanes write 0)
            h0 = p[0]; h1 = p[1]; h2 = p[2];   // read back for next step
        }
        xq = xn;
    }

    // ---- linear head: reduce h[k]*lw over each 16-lane slot ----
    const float lw = un ? lin_w[k] : 0.f;
    float pa = hk * lw;                  // lanes k>=10 contribute 0
    pa += __shfl_xor(pa, 1, 16);
    pa += __shfl_xor(pa, 2, 16);
    pa += __shfl_xor(pa, 4, 16);
    pa += __shfl_xor(pa, 8, 16);
    if (k == 0 && b < n_elem) out[b] = pa + lin_b[0];
}

extern "C" void kernel_launch(void* const* d_in, const int* in_sizes, int n_in,
                              void* d_out, int out_size, void* d_ws, size_t ws_size,
                              hipStream_t stream) {
    const float* x        = (const float*)d_in[0];
    const float* w_ih_mu  = (const float*)d_in[1];
    const float* w_ih_rho = (const float*)d_in[2];
    const float* w_hh_mu  = (const float*)d_in[3];
    const float* w_hh_rho = (const float*)d_in[4];
    const float* b_mu     = (const float*)d_in[5];
    const float* b_rho    = (const float*)d_in[6];
    const float* eps_ih   = (const float*)d_in[7];
    const float* eps_hh   = (const float*)d_in[8];
    const float* eps_b    = (const float*)d_in[9];
    const float* lin_w    = (const float*)d_in[10];
    const float* lin_b    = (const float*)d_in[11];
    float* out = (float*)d_out;

    const int n_b = in_sizes[0] / T_LEN;     // 8192
    dim3 grid((n_b + 3) / 4), block(64);     // 2048 blocks = 2 waves/SIMD exact
    hipLaunchKernelGGL(bayes_lstm_kernel, grid, block, 0, stream,
                       x, w_ih_mu, w_ih_rho, w_hh_mu, w_hh_rho, b_mu, b_rho,
                       eps_ih, eps_hh, eps_b, lin_w, lin_b, out, n_b);
}